// Round 1
// baseline (141.430 us; speedup 1.0000x reference)
//
#include <hip/hip_runtime.h>
#include <math.h>

// AFM: B=4096, F=24, D=64, A=64, P=F*(F-1)/2=276
#define NF 24
#define ND 64
#define NA 64
#define NP 276
#define NT 320   // 5 waves per block, one block per batch element

__global__ __launch_bounds__(NT) void afm_fp32_kernel(
    const float* __restrict__ x,
    const float* __restrict__ Wa,
    const float* __restrict__ ba,
    const float* __restrict__ Wp,
    const float* __restrict__ bp,
    const float* __restrict__ Wfc,
    const float* __restrict__ bfc,
    float* __restrict__ out)
{
    const int b = blockIdx.x;
    const int tid = (int)threadIdx.x;
    const int lane = tid & 63;
    const int wid = tid >> 6;

    __shared__ float xs[NF][ND + 1];       // padded
    __shared__ float attn_s[NP];
    __shared__ int rr_s[NP];
    __shared__ int cc_s[NP];
    __shared__ float red_s[NT / 64];
    __shared__ float ao_s[NT / 64][ND];

    // stage x[b] into LDS
    const float* xb = x + (size_t)b * (NF * ND);
    for (int i = tid; i < NF * ND; i += NT) {
        xs[i >> 6][i & 63] = xb[i];
    }

    // pair index (r,c) for this thread's pair p=tid (triu_indices order)
    int r = 0, c = 0;
    if (tid < NP) {
        int rem = tid;
        while (rem >= NF - 1 - r) { rem -= NF - 1 - r; ++r; }
        c = r + 1 + rem;
        rr_s[tid] = r;
        cc_s[tid] = c;
    }
    __syncthreads();

    // ---- per-pair MLP: h = relu(ip @ Wa + ba); logit = h @ Wp + bp ----
    float logit = -INFINITY;
    if (tid < NP) {
        float acc[NA];
        #pragma unroll
        for (int a = 0; a < NA; ++a) acc[a] = ba[a];   // uniform (scalar) loads
        for (int d = 0; d < ND; ++d) {
            float ip = xs[r][d] * xs[c][d];
            const float* __restrict__ wrow = Wa + d * NA;  // wave-uniform address -> s_load
            #pragma unroll
            for (int a = 0; a < NA; ++a) acc[a] = fmaf(ip, wrow[a], acc[a]);
        }
        float lg = bp[0];
        #pragma unroll
        for (int a = 0; a < NA; ++a) lg = fmaf(fmaxf(acc[a], 0.0f), Wp[a], lg);
        logit = lg;
    }

    // ---- softmax over the 276 pairs (block-wide) ----
    float m = logit;
    #pragma unroll
    for (int off = 32; off > 0; off >>= 1)
        m = fmaxf(m, __shfl_xor(m, off));
    if (lane == 0) red_s[wid] = m;
    __syncthreads();
    m = red_s[0];
    #pragma unroll
    for (int w = 1; w < NT / 64; ++w) m = fmaxf(m, red_s[w]);

    float e = (tid < NP) ? __expf(logit - m) : 0.0f;
    float s = e;
    #pragma unroll
    for (int off = 32; off > 0; off >>= 1)
        s += __shfl_xor(s, off);
    __syncthreads();                 // red_s reuse hazard
    if (lane == 0) red_s[wid] = s;
    __syncthreads();
    s = red_s[0];
    #pragma unroll
    for (int w = 1; w < NT / 64; ++w) s += red_s[w];
    const float inv = 1.0f / s;
    if (tid < NP) attn_s[tid] = e * inv;
    __syncthreads();

    // ---- attn_output[d] = sum_p attn[p] * ip[p][d] ----
    {
        float part = 0.0f;
        for (int p = wid; p < NP; p += NT / 64) {   // p wave-uniform -> LDS broadcasts
            float w = attn_s[p];
            part = fmaf(w * xs[rr_s[p]][lane], xs[cc_s[p]][lane], part);
        }
        ao_s[wid][lane] = part;
    }
    __syncthreads();

    // ---- out[b] = attn_output @ Wfc + bfc ----
    if (tid < ND) {
        float ao = 0.0f;
        #pragma unroll
        for (int w = 0; w < NT / 64; ++w) ao += ao_s[w][tid];
        float v = ao * Wfc[tid];
        #pragma unroll
        for (int off = 32; off > 0; off >>= 1)
            v += __shfl_xor(v, off);
        if (tid == 0) out[b] = v + bfc[0];
    }
}

extern "C" void kernel_launch(void* const* d_in, const int* in_sizes, int n_in,
                              void* d_out, int out_size, void* d_ws, size_t ws_size,
                              hipStream_t stream) {
    const float* x   = (const float*)d_in[0];
    const float* Wa  = (const float*)d_in[1];
    const float* ba  = (const float*)d_in[2];
    const float* Wp  = (const float*)d_in[3];
    const float* bp  = (const float*)d_in[4];
    const float* Wfc = (const float*)d_in[5];
    const float* bfc = (const float*)d_in[6];
    float* out = (float*)d_out;

    const int B = in_sizes[0] / (NF * ND);
    hipLaunchKernelGGL(afm_fp32_kernel, dim3(B), dim3(NT), 0, stream,
                       x, Wa, ba, Wp, bp, Wfc, bfc, out);
}

// Round 6
// 76.899 us; speedup vs baseline: 1.8392x; 1.8392x over previous
//
#include <hip/hip_runtime.h>
#include <hip/hip_bf16.h>
#include <math.h>

// AFM: B=4096, F=24, D=64, A=64, P=F*(F-1)/2=276
#define NF 24
#define ND 64
#define NA 64
#define NP 276
#define NTILE 18     // ceil(276/16) row-tiles of 16 pairs
#define NT 256       // 4 waves per block, one block per batch element

typedef short bf16x8 __attribute__((ext_vector_type(8)));
typedef float f32x4  __attribute__((ext_vector_type(4)));

__device__ __forceinline__ short f2bf(float f) {
    __hip_bfloat16 h = __float2bfloat16(f);      // RNE
    union { __hip_bfloat16 h; unsigned short u; } cv;
    cv.h = h;
    return (short)cv.u;
}
__device__ __forceinline__ float bf2f(short s) {
    union { unsigned u; float f; } cv;
    cv.u = ((unsigned)(unsigned short)s) << 16;
    return cv.f;
}

__global__ __launch_bounds__(NT) void afm_mfma_kernel(
    const float* __restrict__ x,
    const float* __restrict__ Wa,
    const float* __restrict__ ba,
    const float* __restrict__ Wp,
    const float* __restrict__ bp,
    const float* __restrict__ Wfc,
    const float* __restrict__ bfc,
    float* __restrict__ out)
{
    const int b    = blockIdx.x;
    const int tid  = (int)threadIdx.x;
    const int lane = tid & 63;
    const int wid  = tid >> 6;
    const int lg   = lane >> 4;   // k-group 0..3
    const int li   = lane & 15;   // A-row / B-col within fragment

    __shared__ float xs[NF][68];       // float4-aligned rows
    __shared__ float logits_s[NP];
    __shared__ float attn_s[NP];
    __shared__ int   rr_s[NP];
    __shared__ int   cc_s[NP];
    __shared__ float redA[4], redB[4];
    __shared__ float ao_s[4][ND];

    // ---- stage x[b] into LDS ----
    const float* xb = x + (size_t)b * (NF * ND);
    for (int i = tid; i < NF * ND; i += NT)
        xs[i >> 6][i & 63] = xb[i];

    // ---- pair tables (triu order) -- STRIDED: NT=256 < NP=276!  (the r2-r5 bug) ----
    for (int p0 = tid; p0 < NP; p0 += NT) {
        int r = 0, rem = p0;
        while (rem >= NF - 1 - r) { rem -= NF - 1 - r; ++r; }
        rr_s[p0] = r;
        cc_s[p0] = r + 1 + rem;
    }

    // ---- B-fragments: Wa (bf16); ba/Wp per-lane ----
    // Fill convention (m89/m97-verified): B col = lane&15, k = (lane>>4)*8 + i,
    // two K=32 MFMAs cover d = kh*32 + lg*8 + i.
    bf16x8 WaF[4][2];
    #pragma unroll
    for (int nt = 0; nt < 4; ++nt)
        #pragma unroll
        for (int kh = 0; kh < 2; ++kh)
            #pragma unroll
            for (int i = 0; i < 8; ++i) {
                int d = kh * 32 + lg * 8 + i;
                WaF[nt][kh][i] = f2bf(Wa[d * NA + nt * 16 + li]);
            }
    float ba_reg[4], wp_reg[4];
    #pragma unroll
    for (int nt = 0; nt < 4; ++nt) {
        ba_reg[nt] = ba[nt * 16 + li];
        wp_reg[nt] = Wp[nt * 16 + li];
    }
    const float bp0 = bp[0];

    __syncthreads();

    // ---- tile loop: ip (hi+lo bf16) -> h=relu(ip@Wa+ba) -> logit = h@Wp+bp ----
    for (int t = wid; t < NTILE; t += 4) {
        int p = t * 16 + li;            // this lane's A-row (pair index)
        bool valid = p < NP;
        int rI = valid ? rr_s[p] : 0;
        int cI = valid ? cc_s[p] : 0;

        bf16x8 Ah[2], Al[2];
        #pragma unroll
        for (int kh = 0; kh < 2; ++kh) {
            int d0 = kh * 32 + lg * 8;
            const float4* pr = reinterpret_cast<const float4*>(&xs[rI][d0]);
            const float4* pc = reinterpret_cast<const float4*>(&xs[cI][d0]);
            float4 r0 = pr[0], r1 = pr[1];
            float4 c0 = pc[0], c1 = pc[1];
            float prod[8] = { r0.x * c0.x, r0.y * c0.y, r0.z * c0.z, r0.w * c0.w,
                              r1.x * c1.x, r1.y * c1.y, r1.z * c1.z, r1.w * c1.w };
            #pragma unroll
            for (int i = 0; i < 8; ++i) {
                float v = valid ? prod[i] : 0.0f;
                short hi = f2bf(v);
                Ah[kh][i] = hi;
                Al[kh][i] = f2bf(v - bf2f(hi));
            }
        }

        f32x4 acc[4];
        #pragma unroll
        for (int nt = 0; nt < 4; ++nt) {
            acc[nt] = (f32x4){0.f, 0.f, 0.f, 0.f};
            acc[nt] = __builtin_amdgcn_mfma_f32_16x16x32_bf16(Ah[0], WaF[nt][0], acc[nt], 0, 0, 0);
            acc[nt] = __builtin_amdgcn_mfma_f32_16x16x32_bf16(Ah[1], WaF[nt][1], acc[nt], 0, 0, 0);
            acc[nt] = __builtin_amdgcn_mfma_f32_16x16x32_bf16(Al[0], WaF[nt][0], acc[nt], 0, 0, 0);
            acc[nt] = __builtin_amdgcn_mfma_f32_16x16x32_bf16(Al[1], WaF[nt][1], acc[nt], 0, 0, 0);
        }

        // logits: relu(acc + ba) . Wp, reduced over the 16 cols of each group
        #pragma unroll
        for (int j = 0; j < 4; ++j) {
            float lsum = 0.f;
            #pragma unroll
            for (int nt = 0; nt < 4; ++nt) {
                float h = fmaxf(acc[nt][j] + ba_reg[nt], 0.f);
                lsum = fmaf(h, wp_reg[nt], lsum);
            }
            #pragma unroll
            for (int off = 8; off >= 1; off >>= 1)
                lsum += __shfl_xor(lsum, off);
            int row = t * 16 + lg * 4 + j;   // C/D: col=lane&15, row=(lane>>4)*4+reg
            if (li == 0 && row < NP)
                logits_s[row] = lsum + bp0;
        }
    }

    __syncthreads();

    // ---- softmax over pairs ----
    float m = -INFINITY;
    for (int p = tid; p < NP; p += NT) m = fmaxf(m, logits_s[p]);
    #pragma unroll
    for (int off = 32; off >= 1; off >>= 1) m = fmaxf(m, __shfl_xor(m, off));
    if (lane == 0) redA[wid] = m;
    __syncthreads();
    m = fmaxf(fmaxf(redA[0], redA[1]), fmaxf(redA[2], redA[3]));

    float se = 0.f;
    for (int p = tid; p < NP; p += NT) se += __expf(logits_s[p] - m);
    #pragma unroll
    for (int off = 32; off >= 1; off >>= 1) se += __shfl_xor(se, off);
    if (lane == 0) redB[wid] = se;
    __syncthreads();
    const float invSE = 1.0f / (redB[0] + redB[1] + redB[2] + redB[3]);

    for (int p = tid; p < NP; p += NT)
        attn_s[p] = __expf(logits_s[p] - m) * invSE;
    __syncthreads();

    // ---- attn_output[d] = sum_p attn[p] * ip[p][d]  (exact fp32) ----
    {
        float part = 0.0f;
        for (int p = wid; p < NP; p += 4) {      // p wave-uniform -> LDS broadcasts
            float w = attn_s[p];
            part = fmaf(w * xs[rr_s[p]][lane], xs[cc_s[p]][lane], part);
        }
        ao_s[wid][lane] = part;
    }
    __syncthreads();

    // ---- out[b] = attn_output @ Wfc + bfc ----
    if (wid == 0) {
        float ao = ao_s[0][lane] + ao_s[1][lane] + ao_s[2][lane] + ao_s[3][lane];
        float v = ao * Wfc[lane];
        #pragma unroll
        for (int off = 32; off >= 1; off >>= 1) v += __shfl_xor(v, off);
        if (lane == 0) out[b] = v + bfc[0];
    }
}

extern "C" void kernel_launch(void* const* d_in, const int* in_sizes, int n_in,
                              void* d_out, int out_size, void* d_ws, size_t ws_size,
                              hipStream_t stream) {
    const float* x   = (const float*)d_in[0];
    const float* Wa  = (const float*)d_in[1];
    const float* ba  = (const float*)d_in[2];
    const float* Wp  = (const float*)d_in[3];
    const float* bp  = (const float*)d_in[4];
    const float* Wfc = (const float*)d_in[5];
    const float* bfc = (const float*)d_in[6];
    float* out = (float*)d_out;

    const int B = in_sizes[0] / (NF * ND);
    hipLaunchKernelGGL(afm_mfma_kernel, dim3(B), dim3(NT), 0, stream,
                       x, Wa, ba, Wp, bp, Wfc, bfc, out);
}

// Round 7
// 62.965 us; speedup vs baseline: 2.2462x; 1.2213x over previous
//
#include <hip/hip_runtime.h>
#include <hip/hip_bf16.h>
#include <math.h>

// AFM: B=4096, F=24, D=64, A=64, P=F*(F-1)/2=276
#define NF 24
#define ND 64
#define NA 64
#define NP 276
#define NTILE 18     // ceil(276/16) row-tiles of 16 pairs
#define NT 256       // 4 waves per block, one block per batch element

typedef short bf16x8 __attribute__((ext_vector_type(8)));
typedef float f32x4  __attribute__((ext_vector_type(4)));

__device__ __forceinline__ short f2bf(float f) {
    __hip_bfloat16 h = __float2bfloat16(f);      // RNE
    union { __hip_bfloat16 h; unsigned short u; } cv;
    cv.h = h;
    return (short)cv.u;
}
__device__ __forceinline__ float bf2f(short s) {
    union { unsigned u; float f; } cv;
    cv.u = ((unsigned)(unsigned short)s) << 16;
    return cv.f;
}

// ---- prep: pack per-lane Wa / Wfc(hi,lo) MFMA fragments into ws (bf16) ----
// waF layout: [lane 64][chunk 8 = nt*2+kh][8 bf16]   (8 KiB)
// wfcF layout: [lane 64][kh 2][8 bf16]               (2 KiB), col0=hi col1=lo
__global__ __launch_bounds__(64) void afm_prep_kernel(
    const float* __restrict__ Wa,
    const float* __restrict__ Wfc,
    short* __restrict__ ws)
{
    const int l  = (int)threadIdx.x;
    const int lg = l >> 4, li = l & 15;
    short* waF  = ws;
    short* wfcF = ws + 64 * 64;
    #pragma unroll
    for (int nt = 0; nt < 4; ++nt)
        #pragma unroll
        for (int kh = 0; kh < 2; ++kh)
            #pragma unroll
            for (int i = 0; i < 8; ++i) {
                int d = kh * 32 + lg * 8 + i;
                waF[l * 64 + (nt * 2 + kh) * 8 + i] = f2bf(Wa[d * NA + nt * 16 + li]);
            }
    #pragma unroll
    for (int kh = 0; kh < 2; ++kh)
        #pragma unroll
        for (int i = 0; i < 8; ++i) {
            int d = kh * 32 + lg * 8 + i;
            float w = Wfc[d];
            short hi = f2bf(w);
            short lo = f2bf(w - bf2f(hi));
            wfcF[l * 16 + kh * 8 + i] = (li == 0) ? hi : ((li == 1) ? lo : (short)0);
        }
}

__global__ __launch_bounds__(NT) void afm_mfma_kernel(
    const float* __restrict__ x,
    const float* __restrict__ ba,
    const float* __restrict__ Wp,
    const float* __restrict__ bfc,
    const short* __restrict__ ws,
    float* __restrict__ out)
{
    const int b    = blockIdx.x;
    const int tid  = (int)threadIdx.x;
    const int lane = tid & 63;
    const int wid  = tid >> 6;
    const int lg   = lane >> 4;   // k-group 0..3
    const int li   = lane & 15;   // A-row / B-col within fragment

    __shared__ float xs[NF][68];       // float4-aligned rows
    __shared__ float logits_s[NP];
    __shared__ float v_s[NP];
    __shared__ int   rr_s[NP];
    __shared__ int   cc_s[NP];
    __shared__ float redA[4], redB[4], redC[4];

    // ---- stage x[b] into LDS ----
    const float* xb = x + (size_t)b * (NF * ND);
    for (int i = tid; i < NF * ND; i += NT)
        xs[i >> 6][i & 63] = xb[i];

    // ---- pair tables (triu order), strided (NP > NT) ----
    for (int p0 = tid; p0 < NP; p0 += NT) {
        int r = 0, rem = p0;
        while (rem >= NF - 1 - r) { rem -= NF - 1 - r; ++r; }
        rr_s[p0] = r;
        cc_s[p0] = r + 1 + rem;
    }

    // ---- fragments from ws: 8+2 vector loads, no cvt ----
    const bf16x8* waF  = (const bf16x8*)ws;              // [64][8]
    const bf16x8* wfcF = (const bf16x8*)(ws + 64 * 64);  // [64][2]
    bf16x8 WaF[4][2];
    #pragma unroll
    for (int nt = 0; nt < 4; ++nt)
        #pragma unroll
        for (int kh = 0; kh < 2; ++kh)
            WaF[nt][kh] = waF[lane * 8 + nt * 2 + kh];
    bf16x8 WfcF[2] = { wfcF[lane * 2 + 0], wfcF[lane * 2 + 1] };

    float ba_reg[4], wp_reg[4];
    #pragma unroll
    for (int nt = 0; nt < 4; ++nt) {
        ba_reg[nt] = ba[nt * 16 + li];
        wp_reg[nt] = Wp[nt * 16 + li];
    }
    // bp dropped: softmax is invariant to a uniform logit shift.

    __syncthreads();

    // ---- tile loop: ip (hi+lo bf16) -> logits (ip@Wa->relu->@Wp), v = ip@Wfc ----
    for (int t = wid; t < NTILE; t += 4) {
        int p = t * 16 + li;            // this lane's A-row (pair index)
        bool valid = p < NP;
        int rI = valid ? rr_s[p] : 0;
        int cI = valid ? cc_s[p] : 0;

        bf16x8 Ah[2], Al[2];
        #pragma unroll
        for (int kh = 0; kh < 2; ++kh) {
            int d0 = kh * 32 + lg * 8;
            const float4* pr = reinterpret_cast<const float4*>(&xs[rI][d0]);
            const float4* pc = reinterpret_cast<const float4*>(&xs[cI][d0]);
            float4 r0 = pr[0], r1 = pr[1];
            float4 c0 = pc[0], c1 = pc[1];
            float prod[8] = { r0.x * c0.x, r0.y * c0.y, r0.z * c0.z, r0.w * c0.w,
                              r1.x * c1.x, r1.y * c1.y, r1.z * c1.z, r1.w * c1.w };
            #pragma unroll
            for (int i = 0; i < 8; ++i) {
                float v = valid ? prod[i] : 0.0f;
                short hi = f2bf(v);
                Ah[kh][i] = hi;
                Al[kh][i] = f2bf(v - bf2f(hi));
            }
        }

        f32x4 acc[4];
        #pragma unroll
        for (int nt = 0; nt < 4; ++nt) {
            acc[nt] = (f32x4){0.f, 0.f, 0.f, 0.f};
            acc[nt] = __builtin_amdgcn_mfma_f32_16x16x32_bf16(Ah[0], WaF[nt][0], acc[nt], 0, 0, 0);
            acc[nt] = __builtin_amdgcn_mfma_f32_16x16x32_bf16(Ah[1], WaF[nt][1], acc[nt], 0, 0, 0);
            acc[nt] = __builtin_amdgcn_mfma_f32_16x16x32_bf16(Al[0], WaF[nt][0], acc[nt], 0, 0, 0);
            acc[nt] = __builtin_amdgcn_mfma_f32_16x16x32_bf16(Al[1], WaF[nt][1], acc[nt], 0, 0, 0);
        }
        f32x4 accv = (f32x4){0.f, 0.f, 0.f, 0.f};
        accv = __builtin_amdgcn_mfma_f32_16x16x32_bf16(Ah[0], WfcF[0], accv, 0, 0, 0);
        accv = __builtin_amdgcn_mfma_f32_16x16x32_bf16(Ah[1], WfcF[1], accv, 0, 0, 0);
        accv = __builtin_amdgcn_mfma_f32_16x16x32_bf16(Al[0], WfcF[0], accv, 0, 0, 0);
        accv = __builtin_amdgcn_mfma_f32_16x16x32_bf16(Al[1], WfcF[1], accv, 0, 0, 0);

        // logits: relu(acc + ba) . Wp ; v: cols 0(hi)+1(lo) -> same 16-lane reduce
        #pragma unroll
        for (int j = 0; j < 4; ++j) {
            float lsum = 0.f;
            #pragma unroll
            for (int nt = 0; nt < 4; ++nt) {
                float h = fmaxf(acc[nt][j] + ba_reg[nt], 0.f);
                lsum = fmaf(h, wp_reg[nt], lsum);
            }
            float vv = accv[j];
            #pragma unroll
            for (int off = 8; off >= 1; off >>= 1) {
                lsum += __shfl_xor(lsum, off);
                vv   += __shfl_xor(vv, off);
            }
            int row = t * 16 + lg * 4 + j;   // C/D: col=lane&15, row=(lane>>4)*4+reg
            if (li == 0 && row < NP) {
                logits_s[row] = lsum;
                v_s[row] = vv;
            }
        }
    }

    __syncthreads();

    // ---- softmax over pairs fused with output: out = sum(e*v)/sum(e) + bfc ----
    float m = -INFINITY;
    for (int p = tid; p < NP; p += NT) m = fmaxf(m, logits_s[p]);
    #pragma unroll
    for (int off = 32; off >= 1; off >>= 1) m = fmaxf(m, __shfl_xor(m, off));
    if (lane == 0) redA[wid] = m;
    __syncthreads();
    m = fmaxf(fmaxf(redA[0], redA[1]), fmaxf(redA[2], redA[3]));

    float se = 0.f, sev = 0.f;
    for (int p = tid; p < NP; p += NT) {
        float e = __expf(logits_s[p] - m);
        se += e;
        sev = fmaf(e, v_s[p], sev);
    }
    #pragma unroll
    for (int off = 32; off >= 1; off >>= 1) {
        se  += __shfl_xor(se, off);
        sev += __shfl_xor(sev, off);
    }
    if (lane == 0) { redB[wid] = se; redC[wid] = sev; }
    __syncthreads();
    if (tid == 0) {
        float SE = redB[0] + redB[1] + redB[2] + redB[3];
        float SV = redC[0] + redC[1] + redC[2] + redC[3];
        out[b] = SV / SE + bfc[0];
    }
}

extern "C" void kernel_launch(void* const* d_in, const int* in_sizes, int n_in,
                              void* d_out, int out_size, void* d_ws, size_t ws_size,
                              hipStream_t stream) {
    const float* x   = (const float*)d_in[0];
    const float* Wa  = (const float*)d_in[1];
    const float* ba  = (const float*)d_in[2];
    const float* Wp  = (const float*)d_in[3];
    // d_in[4] = bp  (unused: softmax shift-invariant)
    const float* Wfc = (const float*)d_in[5];
    const float* bfc = (const float*)d_in[6];
    float* out = (float*)d_out;
    short* ws  = (short*)d_ws;

    const int B = in_sizes[0] / (NF * ND);
    hipLaunchKernelGGL(afm_prep_kernel, dim3(1), dim3(64), 0, stream, Wa, Wfc, ws);
    hipLaunchKernelGGL(afm_mfma_kernel, dim3(B), dim3(NT), 0, stream,
                       x, ba, Wp, bfc, ws, out);
}

// Round 8
// 49.895 us; speedup vs baseline: 2.8345x; 1.2619x over previous
//
#include <hip/hip_runtime.h>
#include <hip/hip_bf16.h>
#include <math.h>

// AFM: B=4096, F=24, D=64, A=64, P=F*(F-1)/2=276
#define NF 24
#define ND 64
#define NA 64
#define NP 276
#define NPAD 288     // padded pair count (18 tiles of 16)
#define NTILE 18
#define NT 256       // 4 waves per block, one block per batch element

typedef short bf16x8 __attribute__((ext_vector_type(8)));
typedef float f32x4  __attribute__((ext_vector_type(4)));

__device__ __forceinline__ short f2bf(float f) {
    __hip_bfloat16 h = __float2bfloat16(f);      // RNE
    union { __hip_bfloat16 h; unsigned short u; } cv;
    cv.h = h;
    return (short)cv.u;
}
__device__ __forceinline__ float bf2f(short s) {
    union { unsigned u; float f; } cv;
    cv.u = ((unsigned)(unsigned short)s) << 16;
    return cv.f;
}

// ws layout (shorts):
//   [0, 4096)    waF:  [lane 64][chunk 8 = nt*2+kh][8 bf16]
//   [4096, 5120) wfcF: [lane 64][kh 2][8 bf16]  (col0=hi, col1=lo)
//   [5120, ...)  rc:   288 ints, packed (r<<16)|c, pairs padded with (0,0)
__global__ __launch_bounds__(64) void afm_prep_kernel(
    const float* __restrict__ Wa,
    const float* __restrict__ Wfc,
    short* __restrict__ ws)
{
    const int l  = (int)threadIdx.x;
    const int lg = l >> 4, li = l & 15;
    short* waF  = ws;
    short* wfcF = ws + 64 * 64;
    int*   rc   = (int*)(ws + 64 * 64 + 64 * 16);
    #pragma unroll
    for (int nt = 0; nt < 4; ++nt)
        #pragma unroll
        for (int kh = 0; kh < 2; ++kh)
            #pragma unroll
            for (int i = 0; i < 8; ++i) {
                int d = kh * 32 + lg * 8 + i;
                waF[l * 64 + (nt * 2 + kh) * 8 + i] = f2bf(Wa[d * NA + nt * 16 + li]);
            }
    #pragma unroll
    for (int kh = 0; kh < 2; ++kh)
        #pragma unroll
        for (int i = 0; i < 8; ++i) {
            int d = kh * 32 + lg * 8 + i;
            float w = Wfc[d];
            short hi = f2bf(w);
            short lo = f2bf(w - bf2f(hi));
            wfcF[l * 16 + kh * 8 + i] = (li == 0) ? hi : ((li == 1) ? lo : (short)0);
        }
    for (int p0 = l; p0 < NPAD; p0 += 64) {
        int r = 0, c = 0;
        if (p0 < NP) {
            int rem = p0;
            while (rem >= NF - 1 - r) { rem -= NF - 1 - r; ++r; }
            c = r + 1 + rem;
        }
        rc[p0] = (r << 16) | c;
    }
}

__global__ __launch_bounds__(NT) void afm_mfma_kernel(
    const float* __restrict__ x,
    const float* __restrict__ ba,
    const float* __restrict__ Wp,
    const float* __restrict__ bfc,
    const short* __restrict__ ws,
    float* __restrict__ out)
{
    const int b    = blockIdx.x;
    const int tid  = (int)threadIdx.x;
    const int lane = tid & 63;
    const int wid  = tid >> 6;
    const int lg   = lane >> 4;   // k-group 0..3
    const int li   = lane & 15;   // A-row / B-col within fragment

    __shared__ float xs[NF][68];       // float4-aligned rows
    __shared__ float logits_s[NP];
    __shared__ float v_s[NP];
    __shared__ int   rc_s[NPAD];
    __shared__ float redA[4], redB[4], redC[4];

    // ---- stage x[b] into LDS (float4) ----
    const float4* xb4 = (const float4*)(x + (size_t)b * (NF * ND));
    for (int i = tid; i < NF * ND / 4; i += NT) {
        float4 v = xb4[i];
        *(float4*)&xs[i >> 4][(i & 15) * 4] = v;
    }

    // ---- pair table from ws (precomputed, padded) ----
    const int* rc = (const int*)(ws + 64 * 64 + 64 * 16);
    for (int i = tid; i < NPAD; i += NT) rc_s[i] = rc[i];

    // ---- fragments from ws: 10 vector loads, no cvt ----
    const bf16x8* waF  = (const bf16x8*)ws;              // [64][8]
    const bf16x8* wfcF = (const bf16x8*)(ws + 64 * 64);  // [64][2]
    bf16x8 WaF[4][2];
    #pragma unroll
    for (int nt = 0; nt < 4; ++nt)
        #pragma unroll
        for (int kh = 0; kh < 2; ++kh)
            WaF[nt][kh] = waF[lane * 8 + nt * 2 + kh];
    bf16x8 WfcF[2] = { wfcF[lane * 2 + 0], wfcF[lane * 2 + 1] };

    float ba_reg[4], wp_reg[4];
    #pragma unroll
    for (int nt = 0; nt < 4; ++nt) {
        ba_reg[nt] = ba[nt * 16 + li];
        wp_reg[nt] = Wp[nt * 16 + li];
    }
    // bp dropped: softmax is invariant to a uniform logit shift.

    __syncthreads();

    // ---- tile loop: ip(bf16) -> logits (ip@Wa->relu->@Wp), v = ip@Wfc ----
    for (int t = wid; t < NTILE; t += 4) {
        int p  = t * 16 + li;           // this lane's A-row (pair index, padded)
        int pr = rc_s[p];
        int rI = pr >> 16, cI = pr & 0xffff;

        bf16x8 Ah[2];
        #pragma unroll
        for (int kh = 0; kh < 2; ++kh) {
            int d0 = kh * 32 + lg * 8;
            const float4* prp = reinterpret_cast<const float4*>(&xs[rI][d0]);
            const float4* pcp = reinterpret_cast<const float4*>(&xs[cI][d0]);
            float4 r0 = prp[0], r1 = prp[1];
            float4 c0 = pcp[0], c1 = pcp[1];
            Ah[kh][0] = f2bf(r0.x * c0.x);
            Ah[kh][1] = f2bf(r0.y * c0.y);
            Ah[kh][2] = f2bf(r0.z * c0.z);
            Ah[kh][3] = f2bf(r0.w * c0.w);
            Ah[kh][4] = f2bf(r1.x * c1.x);
            Ah[kh][5] = f2bf(r1.y * c1.y);
            Ah[kh][6] = f2bf(r1.z * c1.z);
            Ah[kh][7] = f2bf(r1.w * c1.w);
        }

        f32x4 acc[4];
        #pragma unroll
        for (int nt = 0; nt < 4; ++nt) {
            acc[nt] = (f32x4){0.f, 0.f, 0.f, 0.f};
            acc[nt] = __builtin_amdgcn_mfma_f32_16x16x32_bf16(Ah[0], WaF[nt][0], acc[nt], 0, 0, 0);
            acc[nt] = __builtin_amdgcn_mfma_f32_16x16x32_bf16(Ah[1], WaF[nt][1], acc[nt], 0, 0, 0);
        }
        f32x4 accv = (f32x4){0.f, 0.f, 0.f, 0.f};
        accv = __builtin_amdgcn_mfma_f32_16x16x32_bf16(Ah[0], WfcF[0], accv, 0, 0, 0);
        accv = __builtin_amdgcn_mfma_f32_16x16x32_bf16(Ah[1], WfcF[1], accv, 0, 0, 0);

        // logits: relu(acc + ba) . Wp (16-lane tree); v: col0+col1 via 1 shfl
        #pragma unroll
        for (int j = 0; j < 4; ++j) {
            float lsum = 0.f;
            #pragma unroll
            for (int nt = 0; nt < 4; ++nt) {
                float h = fmaxf(acc[nt][j] + ba_reg[nt], 0.f);
                lsum = fmaf(h, wp_reg[nt], lsum);
            }
            #pragma unroll
            for (int off = 8; off >= 1; off >>= 1)
                lsum += __shfl_xor(lsum, off);
            float vv = accv[j] + __shfl_xor(accv[j], 1);   // cols 0(hi)+1(lo)
            int row = t * 16 + lg * 4 + j;   // C/D: col=lane&15, row=(lane>>4)*4+reg
            if (li == 0 && row < NP) {
                logits_s[row] = lsum;
                v_s[row] = vv;
            }
        }
    }

    __syncthreads();

    // ---- softmax over pairs fused with output: out = sum(e*v)/sum(e) + bfc ----
    float m = -INFINITY;
    for (int p = tid; p < NP; p += NT) m = fmaxf(m, logits_s[p]);
    #pragma unroll
    for (int off = 32; off >= 1; off >>= 1) m = fmaxf(m, __shfl_xor(m, off));
    if (lane == 0) redA[wid] = m;
    __syncthreads();
    m = fmaxf(fmaxf(redA[0], redA[1]), fmaxf(redA[2], redA[3]));

    float se = 0.f, sev = 0.f;
    for (int p = tid; p < NP; p += NT) {
        float e = __expf(logits_s[p] - m);
        se += e;
        sev = fmaf(e, v_s[p], sev);
    }
    #pragma unroll
    for (int off = 32; off >= 1; off >>= 1) {
        se  += __shfl_xor(se, off);
        sev += __shfl_xor(sev, off);
    }
    if (lane == 0) { redB[wid] = se; redC[wid] = sev; }
    __syncthreads();
    if (tid == 0) {
        float SE = redB[0] + redB[1] + redB[2] + redB[3];
        float SV = redC[0] + redC[1] + redC[2] + redC[3];
        out[b] = SV / SE + bfc[0];
    }
}

extern "C" void kernel_launch(void* const* d_in, const int* in_sizes, int n_in,
                              void* d_out, int out_size, void* d_ws, size_t ws_size,
                              hipStream_t stream) {
    const float* x   = (const float*)d_in[0];
    const float* Wa  = (const float*)d_in[1];
    const float* ba  = (const float*)d_in[2];
    const float* Wp  = (const float*)d_in[3];
    // d_in[4] = bp  (unused: softmax shift-invariant)
    const float* Wfc = (const float*)d_in[5];
    const float* bfc = (const float*)d_in[6];
    float* out = (float*)d_out;
    short* ws  = (short*)d_ws;

    const int B = in_sizes[0] / (NF * ND);
    hipLaunchKernelGGL(afm_prep_kernel, dim3(1), dim3(64), 0, stream, Wa, Wfc, ws);
    hipLaunchKernelGGL(afm_mfma_kernel, dim3(B), dim3(NT), 0, stream,
                       x, ba, Wp, bfc, ws, out);
}

// Round 10
// 36.245 us; speedup vs baseline: 3.9021x; 1.3766x over previous
//
#include <hip/hip_runtime.h>
#include <hip/hip_bf16.h>
#include <math.h>

// AFM: B=4096, F=24, D=64, A=64, P=F*(F-1)/2=276
#define NF 24
#define ND 64
#define NA 64
#define NP 276
#define NPAD 288
#define NTILE 18
#define NT 256      // 4 waves per block; wave w handles batch blockIdx*4+w
#define BPB 4

typedef short bf16x8 __attribute__((ext_vector_type(8)));
typedef float f32x4  __attribute__((ext_vector_type(4)));

__device__ __forceinline__ short f2bf(float f) {
    __hip_bfloat16 h = __float2bfloat16(f);      // RNE
    union { __hip_bfloat16 h; unsigned short u; } cv;
    cv.h = h;
    return (short)cv.u;
}
__device__ __forceinline__ float bf2f(short s) {
    union { unsigned u; float f; } cv;
    cv.u = ((unsigned)(unsigned short)s) << 16;
    return cv.f;
}

// ---- DPP helpers (VALU-pipe cross-lane, no LDS); ctrl must be constexpr ----
template <int CTRL, int RMASK>
__device__ __forceinline__ float dpp_add_step(float v) {
    int moved = __builtin_amdgcn_update_dpp(0, __float_as_int(v), CTRL, RMASK, 0xf, true);
    return v + __int_as_float(moved);
}
template <int CTRL, int RMASK>
__device__ __forceinline__ float dpp_max_step(float v) {
    int moved = __builtin_amdgcn_update_dpp(__float_as_int(v), __float_as_int(v), CTRL, RMASK, 0xf, false);
    return fmaxf(v, __int_as_float(moved));
}
// sum of each 16-lane row, result valid at lane 0 of the row (row_shl)
__device__ __forceinline__ float row16_sum0(float v) {
    v = dpp_add_step<0x101, 0xf>(v);   // row_shl 1
    v = dpp_add_step<0x102, 0xf>(v);   // row_shl 2
    v = dpp_add_step<0x104, 0xf>(v);   // row_shl 4
    v = dpp_add_step<0x108, 0xf>(v);   // row_shl 8
    return v;
}
__device__ __forceinline__ float wave_sum(float v) {
    v = dpp_add_step<0x111, 0xf>(v);   // row_shr 1
    v = dpp_add_step<0x112, 0xf>(v);   // row_shr 2
    v = dpp_add_step<0x114, 0xf>(v);   // row_shr 4
    v = dpp_add_step<0x118, 0xf>(v);   // row_shr 8
    v = dpp_add_step<0x142, 0xa>(v);   // row_bcast:15 -> rows 1,3
    v = dpp_add_step<0x143, 0xc>(v);   // row_bcast:31 -> rows 2,3
    return __int_as_float(__builtin_amdgcn_readlane(__float_as_int(v), 63));
}
__device__ __forceinline__ float wave_max(float v) {
    v = dpp_max_step<0x111, 0xf>(v);
    v = dpp_max_step<0x112, 0xf>(v);
    v = dpp_max_step<0x114, 0xf>(v);
    v = dpp_max_step<0x118, 0xf>(v);
    v = dpp_max_step<0x142, 0xa>(v);
    v = dpp_max_step<0x143, 0xc>(v);
    return __int_as_float(__builtin_amdgcn_readlane(__float_as_int(v), 63));
}

// ws layout (shorts):
//   [0, 4096)    waF:  [lane 64][chunk 8 = nt*2+kh][8 bf16]
//   [4096, 5120) wfcF: [lane 64][kh 2][8 bf16]  (col0=hi, col1=lo)
//   [5120, 5696) rc:   288 ints, packed (r<<16)|c, pad pairs = (0,0)
__global__ __launch_bounds__(64) void afm_prep_kernel(
    const float* __restrict__ Wa,
    const float* __restrict__ Wfc,
    short* __restrict__ ws)
{
    const int l  = (int)threadIdx.x;
    const int lg = l >> 4, li = l & 15;
    short* waF  = ws;
    short* wfcF = ws + 64 * 64;
    int*   rc   = (int*)(ws + 64 * 64 + 64 * 16);
    #pragma unroll
    for (int nt = 0; nt < 4; ++nt)
        #pragma unroll
        for (int kh = 0; kh < 2; ++kh)
            #pragma unroll
            for (int i = 0; i < 8; ++i) {
                int d = kh * 32 + lg * 8 + i;
                waF[l * 64 + (nt * 2 + kh) * 8 + i] = f2bf(Wa[d * NA + nt * 16 + li]);
            }
    #pragma unroll
    for (int kh = 0; kh < 2; ++kh)
        #pragma unroll
        for (int i = 0; i < 8; ++i) {
            int d = kh * 32 + lg * 8 + i;
            float w = Wfc[d];
            short hi = f2bf(w);
            short lo = f2bf(w - bf2f(hi));
            wfcF[l * 16 + kh * 8 + i] = (li == 0) ? hi : ((li == 1) ? lo : (short)0);
        }
    for (int p0 = l; p0 < NPAD; p0 += 64) {
        int r = 0, c = 0;
        if (p0 < NP) {
            int rem = p0;
            while (rem >= NF - 1 - r) { rem -= NF - 1 - r; ++r; }
            c = r + 1 + rem;
        }
        rc[p0] = (r << 16) | c;
    }
}

__global__ __launch_bounds__(NT) void afm_mfma_kernel(
    const float* __restrict__ x,
    const float* __restrict__ ba,
    const float* __restrict__ Wp,
    const float* __restrict__ bfc,
    const short* __restrict__ ws,
    float* __restrict__ out)
{
    const int tid  = (int)threadIdx.x;
    const int lane = tid & 63;
    const int wid  = tid >> 6;
    const int b    = blockIdx.x * BPB + wid;   // this wave's batch
    const int lg   = lane >> 4;
    const int li   = lane & 15;

    __shared__ float  xs[BPB][NF][68];   // per-wave x tile (float4-aligned rows)
    __shared__ float2 lv[BPB][NPAD];     // per-wave {logit, v}

    // ---- stage x[b] into this wave's LDS region (no cross-wave deps) ----
    const float4* xb4 = (const float4*)(x + (size_t)b * (NF * ND));
    #pragma unroll
    for (int k = 0; k < 6; ++k) {
        int i = lane + k * 64;           // 0..383
        float4 v = xb4[i];
        *(float4*)&xs[wid][i >> 4][(i & 15) * 4] = v;
    }

    // ---- fragments from ws: 10 vector loads, no cvt ----
    const bf16x8* waF  = (const bf16x8*)ws;              // [64][8]
    const bf16x8* wfcF = (const bf16x8*)(ws + 64 * 64);  // [64][2]
    const int*    rcg  = (const int*)(ws + 64 * 64 + 64 * 16);
    bf16x8 WaF[4][2];
    #pragma unroll
    for (int nt = 0; nt < 4; ++nt)
        #pragma unroll
        for (int kh = 0; kh < 2; ++kh)
            WaF[nt][kh] = waF[lane * 8 + nt * 2 + kh];
    bf16x8 WfcF[2] = { wfcF[lane * 2 + 0], wfcF[lane * 2 + 1] };

    float ba_reg[4], wp_reg[4];
    #pragma unroll
    for (int nt = 0; nt < 4; ++nt) {
        ba_reg[nt] = ba[nt * 16 + li];
        wp_reg[nt] = Wp[nt * 16 + li];
    }

    // in-wave ordering of staging writes vs tile reads (compiler also tracks)
    asm volatile("s_waitcnt lgkmcnt(0)" ::: "memory");

    // ---- tile loop: ip(bf16) -> logits (ip@Wa->relu->@Wp), v = ip@Wfc ----
    for (int t = 0; t < NTILE; ++t) {
        int pr = rcg[t * 16 + li];       // L1-resident pair table
        int rI = pr >> 16, cI = pr & 0xffff;

        bf16x8 Ah[2];
        #pragma unroll
        for (int kh = 0; kh < 2; ++kh) {
            int d0 = kh * 32 + lg * 8;
            const float4* prp = reinterpret_cast<const float4*>(&xs[wid][rI][d0]);
            const float4* pcp = reinterpret_cast<const float4*>(&xs[wid][cI][d0]);
            float4 r0 = prp[0], r1 = prp[1];
            float4 c0 = pcp[0], c1 = pcp[1];
            Ah[kh][0] = f2bf(r0.x * c0.x);
            Ah[kh][1] = f2bf(r0.y * c0.y);
            Ah[kh][2] = f2bf(r0.z * c0.z);
            Ah[kh][3] = f2bf(r0.w * c0.w);
            Ah[kh][4] = f2bf(r1.x * c1.x);
            Ah[kh][5] = f2bf(r1.y * c1.y);
            Ah[kh][6] = f2bf(r1.z * c1.z);
            Ah[kh][7] = f2bf(r1.w * c1.w);
        }

        f32x4 acc[4];
        #pragma unroll
        for (int nt = 0; nt < 4; ++nt) {
            acc[nt] = (f32x4){0.f, 0.f, 0.f, 0.f};
            acc[nt] = __builtin_amdgcn_mfma_f32_16x16x32_bf16(Ah[0], WaF[nt][0], acc[nt], 0, 0, 0);
            acc[nt] = __builtin_amdgcn_mfma_f32_16x16x32_bf16(Ah[1], WaF[nt][1], acc[nt], 0, 0, 0);
        }
        f32x4 accv = (f32x4){0.f, 0.f, 0.f, 0.f};
        accv = __builtin_amdgcn_mfma_f32_16x16x32_bf16(Ah[0], WfcF[0], accv, 0, 0, 0);
        accv = __builtin_amdgcn_mfma_f32_16x16x32_bf16(Ah[1], WfcF[1], accv, 0, 0, 0);

        // epilogue: DPP row reduce (VALU pipe), write {logit, v} at li==0
        #pragma unroll
        for (int j = 0; j < 4; ++j) {
            float lsum = 0.f;
            #pragma unroll
            for (int nt = 0; nt < 4; ++nt) {
                float h = fmaxf(acc[nt][j] + ba_reg[nt], 0.f);
                lsum = fmaf(h, wp_reg[nt], lsum);
            }
            lsum = row16_sum0(lsum);                       // sum over 16 cols -> li==0
            int moved = __builtin_amdgcn_update_dpp(       // quad_perm(1,0,3,2)
                0, __float_as_int(accv[j]), 0xB1, 0xf, 0xf, true);
            float vv = accv[j] + __int_as_float(moved);    // col0(hi)+col1(lo) at li==0
            int row = t * 16 + lg * 4 + j;                 // C/D: col=li, row=lg*4+j
            if (li == 0)
                lv[wid][row] = make_float2(lsum, vv);      // rows>=NP are pad, never read
        }
    }

    asm volatile("s_waitcnt lgkmcnt(0)" ::: "memory");

    // ---- per-wave softmax fused with output ----
    float2 myv[5];
    float m = -INFINITY;
    #pragma unroll
    for (int k = 0; k < 5; ++k) {
        int p = lane + k * 64;
        if (p < NP) { myv[k] = lv[wid][p]; m = fmaxf(m, myv[k].x); }
        else        { myv[k] = make_float2(-INFINITY, 0.f); }
    }
    m = wave_max(m);

    float se = 0.f, sev = 0.f;
    #pragma unroll
    for (int k = 0; k < 5; ++k) {
        int p = lane + k * 64;
        if (p < NP) {
            float e = __expf(myv[k].x - m);
            se += e;
            sev = fmaf(e, myv[k].y, sev);
        }
    }
    se  = wave_sum(se);
    sev = wave_sum(sev);
    if (lane == 0)
        out[b] = sev / se + bfc[0];
}

extern "C" void kernel_launch(void* const* d_in, const int* in_sizes, int n_in,
                              void* d_out, int out_size, void* d_ws, size_t ws_size,
                              hipStream_t stream) {
    const float* x   = (const float*)d_in[0];
    const float* Wa  = (const float*)d_in[1];
    const float* ba  = (const float*)d_in[2];
    const float* Wp  = (const float*)d_in[3];
    // d_in[4] = bp  (unused: softmax shift-invariant)
    const float* Wfc = (const float*)d_in[5];
    const float* bfc = (const float*)d_in[6];
    float* out = (float*)d_out;
    short* ws  = (short*)d_ws;

    const int B = in_sizes[0] / (NF * ND);
    hipLaunchKernelGGL(afm_prep_kernel, dim3(1), dim3(64), 0, stream, Wa, Wfc, ws);
    hipLaunchKernelGGL(afm_mfma_kernel, dim3(B / BPB), dim3(NT), 0, stream,
                       x, ba, Wp, bfc, ws, out);
}